// Round 2
// baseline (419.425 us; speedup 1.0000x reference)
//
#include <hip/hip_runtime.h>

// LSTMSoftAttention on MI355X — R2.
// Shapes: H=1024, N=2048, T=2048, B=16, all fp32.
//
// R2 changes vs R1:
//  * k_main: wave-per-row (was 4-waves-per-row). Score reduction is a
//    64-lane shfl_xor butterfly -> ZERO __syncthreads in the hot loop,
//    so no vmcnt(0) barrier drain; enc is read once, streamed.
//  * k_decfea: wave-per-n computing all 16 batch outputs -> Wd read once
//    (8 MB HBM) instead of 16x (256 MB L2/L3 traffic).
//
// Workspace (floats):
//   dec_fea 32768 | p 32768 | l_part 4096 | l_inv 16 | c_part 256*16*2048

#define HH 1024
#define NNF 2048
#define TTT 2048
#define BB 16
#define NCHUNK 64     // blocks along T in k_main
#define NWCHUNK 256   // wave-chunks = NCHUNK * 4 waves
#define RPW 8         // rows per wave

#define WS_DECFEA 0
#define WS_P      (BB * NNF)                  // 32768
#define WS_LPART  (WS_P + TTT * BB)           // 65536
#define WS_LINV   (WS_LPART + NWCHUNK * BB)   // 69632
#define WS_CPART  (WS_LINV + 16)              // 69648 (69648*4 % 16 == 0)

__device__ __forceinline__ float tanh_fast(float x) {
    // tanh(x) = 1 - 2/(exp(2x)+1); saturates correctly at +-inf.
    float e = __expf(2.0f * x);
    return 1.0f - 2.0f * __builtin_amdgcn_rcpf(e + 1.0f);
}

// dec_fea[b,n] = dot(dec[b,:], Wd[n,:]) + bd[n]
// One wave per n; each wave computes all 16 b outputs so Wd is read once.
__global__ __launch_bounds__(256) void k_decfea(const float* __restrict__ dec,
                                                const float* __restrict__ Wd,
                                                const float* __restrict__ bd,
                                                float* __restrict__ dec_fea) {
    const int n    = (blockIdx.x * 256 + threadIdx.x) >> 6;  // 0..2047
    const int lane = threadIdx.x & 63;
    const float* wr = Wd + (size_t)n * HH;

    float acc[BB];
#pragma unroll
    for (int b = 0; b < BB; ++b) acc[b] = 0.0f;

#pragma unroll
    for (int it = 0; it < 4; ++it) {
        const int h = it * 256 + lane * 4;
        const float4 w4 = *(const float4*)(wr + h);
#pragma unroll
        for (int b = 0; b < BB; ++b) {
            const float4 d4 = *(const float4*)(dec + b * HH + h);
            acc[b] = fmaf(w4.x, d4.x, acc[b]);
            acc[b] = fmaf(w4.y, d4.y, acc[b]);
            acc[b] = fmaf(w4.z, d4.z, acc[b]);
            acc[b] = fmaf(w4.w, d4.w, acc[b]);
        }
    }
#pragma unroll
    for (int b = 0; b < BB; ++b) {
#pragma unroll
        for (int off = 32; off; off >>= 1) acc[b] += __shfl_xor(acc[b], off, 64);
    }
    if (lane == 0) {
        const float bias = bd[n];
#pragma unroll
        for (int b = 0; b < BB; ++b) dec_fea[b * NNF + n] = acc[b] + bias;
    }
}

// Fused scores + unnormalized-softmax context accumulation.
// Grid (NCHUNK, BB), 256 threads = 4 waves. Wave w owns rows
// t = chunk*32 + w*8 .. +7 for batch b; each lane covers 8 float4 segments.
__global__ __launch_bounds__(256, 2) void k_main(const float* __restrict__ enc,
                                                 const int* __restrict__ mask,
                                                 const float* __restrict__ cov,
                                                 const float* __restrict__ wc,
                                                 const float* __restrict__ v,
                                                 float* __restrict__ ws) {
    const int b     = blockIdx.y;
    const int chunk = blockIdx.x;
    const int tid   = threadIdx.x;
    const int lane  = tid & 63;
    const int w     = tid >> 6;
    const int t0    = chunk * (4 * RPW) + w * RPW;
    const int nb    = lane * 4;   // lane's base within each 256-float segment

    const float* dec_fea = ws + WS_DECFEA;
    float* ws_p     = ws + WS_P;
    float* ws_lpart = ws + WS_LPART;
    float* cpart    = ws + WS_CPART;

    float4 d[8], wv[8], vv[8], c[8];
#pragma unroll
    for (int s = 0; s < 8; ++s) {
        const int n = s * 256 + nb;
        d[s]  = *(const float4*)(dec_fea + b * NNF + n);
        wv[s] = *(const float4*)(wc + n);
        vv[s] = *(const float4*)(v + n);
        c[s]  = make_float4(0.f, 0.f, 0.f, 0.f);
    }

    float l_loc = 0.0f;

    for (int r = 0; r < RPW; ++r) {
        const int t = t0 + r;
        const float* row = enc + ((size_t)t * BB + b) * NNF;
        float4 f[8];
#pragma unroll
        for (int s = 0; s < 8; ++s) f[s] = *(const float4*)(row + s * 256 + nb);
        const float cv = cov[t * BB + b];

        float sa = 0.0f;
#pragma unroll
        for (int s = 0; s < 8; ++s) {
            float a;
            a = fmaf(cv, wv[s].x, f[s].x + d[s].x); sa = fmaf(tanh_fast(a), vv[s].x, sa);
            a = fmaf(cv, wv[s].y, f[s].y + d[s].y); sa = fmaf(tanh_fast(a), vv[s].y, sa);
            a = fmaf(cv, wv[s].z, f[s].z + d[s].z); sa = fmaf(tanh_fast(a), vv[s].z, sa);
            a = fmaf(cv, wv[s].w, f[s].w + d[s].w); sa = fmaf(tanh_fast(a), vv[s].w, sa);
        }
        // full-wave butterfly: every lane ends with the row score
#pragma unroll
        for (int off = 32; off; off >>= 1) sa += __shfl_xor(sa, off, 64);

        const bool pad = mask[t * BB + b] != 0;
        const float p = pad ? 0.0f : __expf(sa);
        l_loc += p;
#pragma unroll
        for (int s = 0; s < 8; ++s) {
            c[s].x = fmaf(p, f[s].x, c[s].x);
            c[s].y = fmaf(p, f[s].y, c[s].y);
            c[s].z = fmaf(p, f[s].z, c[s].z);
            c[s].w = fmaf(p, f[s].w, c[s].w);
        }
        if (lane == 0) ws_p[t * BB + b] = p;
    }

    const int wchunk = chunk * 4 + w;
    if (lane == 0) ws_lpart[wchunk * BB + b] = l_loc;
    float* cp = cpart + (size_t)(wchunk * BB + b) * NNF;
#pragma unroll
    for (int s = 0; s < 8; ++s) *(float4*)(cp + s * 256 + nb) = c[s];
}

// l_inv[b] = 1 / sum_j l_part[j,b]   (256 partials per b)
__global__ __launch_bounds__(256) void k_linv(float* __restrict__ ws) {
    __shared__ float lds[256];
    const int tid = threadIdx.x;
    const int b  = tid & (BB - 1);
    const int j0 = tid >> 4;  // 16 groups of 16
    float s = 0.0f;
#pragma unroll
    for (int jj = 0; jj < 16; ++jj) s += ws[WS_LPART + (j0 * 16 + jj) * BB + b];
    lds[tid] = s;
    __syncthreads();
    if (tid < BB) {
        float tot = 0.0f;
#pragma unroll
        for (int k = 0; k < 16; ++k) tot += lds[k * BB + tid];
        ws[WS_LINV + tid] = 1.0f / tot;
    }
}

// c[b,n] = sum_j c_part[j,b,n] * l_inv[b]
__global__ __launch_bounds__(256) void k_finc(const float* __restrict__ ws,
                                              float* __restrict__ out_c) {
    const int gid  = blockIdx.x * 256 + threadIdx.x;
    const int idx4 = gid * 4;
    const int b = idx4 >> 11;
    const int n = idx4 & (NNF - 1);
    float4 s = {0.f, 0.f, 0.f, 0.f};
    for (int j = 0; j < NWCHUNK; ++j) {
        const float4 a = *(const float4*)(ws + WS_CPART + (size_t)(j * BB + b) * NNF + n);
        s.x += a.x; s.y += a.y; s.z += a.z; s.w += a.w;
    }
    const float li = ws[WS_LINV + b];
    s.x *= li; s.y *= li; s.z *= li; s.w *= li;
    *(float4*)(out_c + idx4) = s;
}

// attn = p * l_inv; cov_out = cov + attn
__global__ __launch_bounds__(256) void k_fina(const float* __restrict__ ws,
                                              const float* __restrict__ cov,
                                              float* __restrict__ out_attn,
                                              float* __restrict__ out_cov) {
    const int idx = blockIdx.x * 256 + threadIdx.x;  // t*B + b
    const int b = idx & (BB - 1);
    const float a = ws[WS_P + idx] * ws[WS_LINV + b];
    out_attn[idx] = a;
    out_cov[idx] = cov[idx] + a;
}

extern "C" void kernel_launch(void* const* d_in, const int* in_sizes, int n_in,
                              void* d_out, int out_size, void* d_ws, size_t ws_size,
                              hipStream_t stream) {
    const float* dec  = (const float*)d_in[0];
    const float* enc  = (const float*)d_in[1];
    const int*   mask = (const int*)d_in[2];
    const float* cov  = (const float*)d_in[3];
    const float* Wd   = (const float*)d_in[4];
    const float* bd   = (const float*)d_in[5];
    const float* wc   = (const float*)d_in[6];
    const float* v    = (const float*)d_in[7];
    float* ws  = (float*)d_ws;
    float* out = (float*)d_out;

    float* out_c    = out;                 // (B, N)   32768
    float* out_attn = out + BB * NNF;      // (T, B)   32768
    float* out_cov  = out_attn + TTT * BB; // (T, B)   32768

    // 1. dec_fea: 2048 waves (one per n) -> 512 blocks of 256
    k_decfea<<<512, 256, 0, stream>>>(dec, Wd, bd, ws + WS_DECFEA);

    // 2. fused single pass over enc (256 MiB), barrier-free
    dim3 g2(NCHUNK, BB);
    k_main<<<g2, 256, 0, stream>>>(enc, mask, cov, wc, v, ws);

    // 3. l_inv
    k_linv<<<1, 256, 0, stream>>>(ws);

    // 4. context finalize: B*N/4 = 8192 threads
    k_finc<<<32, 256, 0, stream>>>(ws, out_c);

    // 5. attn + coverage finalize: T*B = 32768 threads
    k_fina<<<128, 256, 0, stream>>>(ws, cov, out_attn, out_cov);
}